// Round 10
// baseline (1466.641 us; speedup 1.0000x reference)
//
#include <hip/hip_runtime.h>
#include <hip/hip_bf16.h>
#include <math.h>

#define N_NODES 100000
#define N_EDGES 1600000
#define HEADS 8
#define HC 128
#define LOG2E 1.44269504f

#define DPB 64                    // dests per bucket
#define NB 1563                   // ceil(100000/64)
#define NBP (NB + 1)              // offsets rows (with end sentinel)
#define NCH 256                   // edge chunks (1.6M/256 = 6250 exact)
#define EPC (N_EDGES / NCH)       // 6250
#define NNODE 512                 // node-role blocks in k_prep
#define ACCP 65                   // padded dest-stride for acc[c][dst]

// ============ K1: fused node transform (blocks >= NCH) + counting sort =======
__global__ __launch_bounds__(512) void k_prep(
    const float* __restrict__ x, const float* __restrict__ W,
    const float* __restrict__ att_s, const float* __restrict__ att_d,
    const int* __restrict__ ei, __hip_bfloat162* __restrict__ h,
    __hip_bfloat16* __restrict__ a_srcb, float* __restrict__ a_dst,
    int* __restrict__ offs, unsigned* __restrict__ stg) {
    __shared__ int smem[2048 + EPC];     // csort: hist[2048] + entries[EPC]
    __shared__ int ws8[8];               // node: reuses smem[0..2048) as sW
    int t = threadIdx.x;
    if (blockIdx.x >= NCH) {
        // ---- node role: h = x@W (bf16), attention logits (pre-scaled LOG2E) --
        float* sW = (float*)smem;
        for (int i = t; i < 16 * HC; i += 512) sW[i] = W[i];
        __syncthreads();
        int lane = t & 63, wv = t >> 6;
        int gw = (blockIdx.x - NCH) * 8 + wv;
        int c0 = 2 * lane;
        float as0 = att_s[c0] * LOG2E, as1 = att_s[c0 + 1] * LOG2E;
        float ad0 = att_d[c0] * LOG2E, ad1 = att_d[c0 + 1] * LOG2E;
        for (int node = gw; node < N_NODES; node += NNODE * 8) {
            float xv = 0.f;
            if (lane < 16) xv = x[node * 16 + lane];
            float acc0 = 0.f, acc1 = 0.f;
#pragma unroll
            for (int k = 0; k < 16; ++k) {
                float xk = __shfl(xv, k);
                acc0 = fmaf(xk, sW[k * HC + c0], acc0);
                acc1 = fmaf(xk, sW[k * HC + c0 + 1], acc1);
            }
            h[node * 64 + lane] = __float22bfloat162_rn(float2{acc0, acc1});
            float ps = acc0 * as0 + acc1 * as1;
            float pd = acc0 * ad0 + acc1 * ad1;
#pragma unroll
            for (int off = 4; off >= 1; off >>= 1) {
                ps += __shfl_xor(ps, off);
                pd += __shfl_xor(pd, off);
            }
            if ((lane & 7) == 0) {
                int hd = lane >> 3;
                a_srcb[node * 8 + hd] = __float2bfloat16(ps);
                a_dst[node * 8 + hd] = pd;
            }
        }
    } else {
        // ---- csort role: bucket-sort chunk edges, write offsets row ----
        int* hist = smem;
        unsigned* entries = (unsigned*)(smem + 2048);
        int c = blockIdx.x;
        hist[t] = 0; hist[t + 512] = 0; hist[t + 1024] = 0; hist[t + 1536] = 0;
        __syncthreads();
        int beg = c * EPC, end = beg + EPC;
        for (int e = beg + t; e < end; e += 512)
            atomicAdd(&hist[ei[N_EDGES + e] >> 6], 1);
        __syncthreads();
        int i0 = 4 * t;
        int v0 = hist[i0], v1 = hist[i0 + 1], v2 = hist[i0 + 2], v3 = hist[i0 + 3];
        int s1 = v0 + v1, s2 = s1 + v2, T = s2 + v3;
        int lane = t & 63, wv = t >> 6;
        int inc = T;
#pragma unroll
        for (int off = 1; off < 64; off <<= 1) {
            int y = __shfl_up(inc, off);
            if (lane >= off) inc += y;
        }
        if (lane == 63) ws8[wv] = inc;
        __syncthreads();
        int wbase = 0;
        for (int k = 0; k < wv; ++k) wbase += ws8[k];
        int e0 = wbase + inc - T;
        hist[i0] = e0; hist[i0 + 1] = e0 + v0;
        hist[i0 + 2] = e0 + s1; hist[i0 + 3] = e0 + s2;
        __syncthreads();
        int row = c * NBP;
        for (int b = t; b < NB; b += 512) offs[row + b] = hist[b];
        if (t == 0) offs[row + NB] = EPC;
        __syncthreads();
        for (int e = beg + t; e < end; e += 512) {
            int src = ei[e], dst = ei[N_EDGES + e];
            int pos = atomicAdd(&hist[dst >> 6], 1);
            entries[pos] = ((unsigned)(dst & 63) << 17) | (unsigned)src;
        }
        __syncthreads();
        unsigned* so = stg + beg;
        for (int i = t; i < EPC; i += 512) so[i] = entries[i];
    }
}

// ============ K2: transpose offs [NCH][NBP] -> offsT [NBP][NCH] ==============
__global__ __launch_bounds__(256) void k_tr(const int* __restrict__ offs,
                                            int* __restrict__ offsT) {
    __shared__ int tile[64][65];
    int b0 = (blockIdx.x >> 2) * 64;
    int c0 = (blockIdx.x & 3) * 64;
    int t = threadIdx.x;
    for (int i = t; i < 4096; i += 256) {
        int cc = i >> 6, bb = i & 63;
        int b = b0 + bb;
        tile[bb][cc] = (b < NBP) ? offs[(c0 + cc) * NBP + b] : 0;
    }
    __syncthreads();
    for (int i = t; i < 4096; i += 256) {
        int bb = i >> 6, cc = i & 63;
        int b = b0 + bb;
        if (b < NBP) offsT[b * NCH + c0 + cc] = tile[bb][cc];
    }
}

// ============ K3: gather — thread-per-edge, LDS atomic accumulators ==========
// One 512-thr block per 64-dest bucket. Each thread fully processes one edge:
// 8 head-weights (exp2 once each), full 256B h-row, 128 ds_add_f32 into
// acc[c*ACCP + dst] (banks spread by random dst). No sort, perfect balance.
__global__ __launch_bounds__(512) void k_gather(
    const __hip_bfloat162* __restrict__ h, const __hip_bfloat16* __restrict__ a_srcb,
    const float* __restrict__ a_dst, const int* __restrict__ offsT,
    const unsigned* __restrict__ stg, const float* __restrict__ bias,
    const float* __restrict__ fc_w, const float* __restrict__ fc_b,
    float* __restrict__ out) {
    __shared__ float acc[HC * ACCP];        // 33.3 KB
    __shared__ float wsum[DPB * 9];         // padded
    __shared__ float sad[DPB * 8];          // staged a_dst for this bucket
    __shared__ int o0_s[NCH];
    __shared__ int myb_s[NCH + 1];
    __shared__ int ws4[4];
    int b = blockIdx.x, t = threadIdx.x;
    int d0 = b * DPB;
    // ---- init: zero acc/wsum, stage a_dst, read offset rows ----
    for (int i = t; i < HC * ACCP; i += 512) acc[i] = 0.f;
    for (int i = t; i < DPB * 9; i += 512) wsum[i] = 0.f;
    {
        int gd = d0 + (t >> 3);
        sad[t] = (gd < N_NODES) ? a_dst[gd * 8 + (t & 7)] : 0.f;
    }
    int o0 = 0, len = 0;
    if (t < NCH) {
        o0 = offsT[b * NCH + t];
        len = offsT[(b + 1) * NCH + t] - o0;
        o0_s[t] = o0;
    }
    // scan of segment lengths (4 waves)
    int lane = t & 63, wv = t >> 6;
    int inc = len;
    if (t < NCH) {
#pragma unroll
        for (int off = 1; off < 64; off <<= 1) {
            int y = __shfl_up(inc, off);
            if (lane >= off) inc += y;
        }
        if (lane == 63) ws4[wv] = inc;
    }
    __syncthreads();
    if (t < NCH) {
        int wbase = 0;
        for (int k = 0; k < wv; ++k) wbase += ws4[k];
        myb_s[t] = wbase + inc - len;
        if (t == NCH - 1) myb_s[NCH] = wbase + inc;
    }
    __syncthreads();
    int etot = myb_s[NCH];
    int selfc = N_NODES - d0; if (selfc > DPB) selfc = DPB;
    int tot_all = etot + selfc;
    // ---- edge loop: one edge per thread ----
    for (int i = t; i < tot_all; i += 512) {
        int src, loc;
        if (i < selfc) { loc = i; src = d0 + i; }
        else {
            int j = i - selfc;
            int lo = 0, hi = NCH - 1;
#pragma unroll
            for (int s = 0; s < 8; ++s) {
                int mid = (lo + hi + 1) >> 1;
                if (myb_s[mid] <= j) lo = mid; else hi = mid - 1;
            }
            unsigned u = stg[lo * EPC + o0_s[lo] + (j - myb_s[lo])];
            loc = (int)(u >> 17);
            src = (int)(u & 0x1FFFF);
        }
        // 8 head weights
        union { uint4 u; __hip_bfloat162 p[4]; } av;
        av.u = *(const uint4*)(a_srcb + (size_t)src * 8);
        float w[8];
#pragma unroll
        for (int k = 0; k < 4; ++k) {
            float2 as2 = __bfloat1622float2(av.p[k]);
            float e0 = as2.x + sad[loc * 8 + 2 * k];
            float e1 = as2.y + sad[loc * 8 + 2 * k + 1];
            e0 = fmaxf(e0, 0.2f * e0);
            e1 = fmaxf(e1, 0.2f * e1);
            w[2 * k] = exp2f(e0);
            w[2 * k + 1] = exp2f(e1);
            atomicAdd(&wsum[loc * 9 + 2 * k], w[2 * k]);
            atomicAdd(&wsum[loc * 9 + 2 * k + 1], w[2 * k + 1]);
        }
        // full h row: 16 x 16B loads, 128 ds_add_f32 (immediate offsets)
        const uint4* hp = (const uint4*)(h + (size_t)src * 64);
#pragma unroll
        for (int k = 0; k < 16; ++k) {
            union { uint4 u; __hip_bfloat162 p[4]; } hv;
            hv.u = hp[k];
#pragma unroll
            for (int p4 = 0; p4 < 4; ++p4) {
                int c = k * 8 + p4 * 2;
                float2 f = __bfloat1622float2(hv.p[p4]);
                atomicAdd(&acc[c * ACCP + loc], w[c >> 4] * f.x);
                atomicAdd(&acc[(c + 1) * ACCP + loc], w[(c + 1) >> 4] * f.y);
            }
        }
    }
    __syncthreads();
    // ---- finalize: 8 threads per dest (one head each, 16 ch) ----
    int l = t >> 3, hh = t & 7;
    int gd = d0 + l;
    if (gd < N_NODES) {
        float inv = 1.f / (wsum[l * 9 + hh] + 1e-16f);
        float p[5] = {0.f, 0.f, 0.f, 0.f, 0.f};
#pragma unroll
        for (int k = 0; k < 16; ++k) {
            int c = hh * 16 + k;
            float ov = fmaxf(acc[c * ACCP + l] * inv + bias[c], 0.f);
#pragma unroll
            for (int j = 0; j < 5; ++j) p[j] = fmaf(ov, fc_w[c * 5 + j], p[j]);
        }
#pragma unroll
        for (int m = 4; m >= 1; m >>= 1) {
#pragma unroll
            for (int j = 0; j < 5; ++j) p[j] += __shfl_xor(p[j], m);
        }
        if (hh == 0) {
            float lg[5], mx = -1e30f;
#pragma unroll
            for (int j = 0; j < 5; ++j) { lg[j] = p[j] + fc_b[j]; mx = fmaxf(mx, lg[j]); }
            float sum = 0.f;
#pragma unroll
            for (int j = 0; j < 5; ++j) sum += __expf(lg[j] - mx);
            float ls = mx + __logf(sum);
#pragma unroll
            for (int j = 0; j < 5; ++j) out[gd * 5 + j] = lg[j] - ls;
        }
    }
}

extern "C" void kernel_launch(void* const* d_in, const int* in_sizes, int n_in,
                              void* d_out, int out_size, void* d_ws, size_t ws_size,
                              hipStream_t stream) {
    const float* x     = (const float*)d_in[0];
    const int*   ei    = (const int*)d_in[1];
    const float* W     = (const float*)d_in[2];
    const float* att_s = (const float*)d_in[3];
    const float* att_d = (const float*)d_in[4];
    const float* bias  = (const float*)d_in[5];
    const float* fc_w  = (const float*)d_in[6];
    const float* fc_b  = (const float*)d_in[7];
    float* out = (float*)d_out;

    char* ws = (char*)d_ws;
    size_t off = 0;
    auto carve = [&](size_t bytes) {
        void* p = ws + off;
        off = (off + bytes + 255) & ~(size_t)255;
        return p;
    };
    __hip_bfloat162* h = (__hip_bfloat162*)carve((size_t)N_NODES * HC * 2);
    __hip_bfloat16* a_srcb = (__hip_bfloat16*)carve((size_t)N_NODES * HEADS * 2);
    float*    a_dst = (float*)   carve((size_t)N_NODES * HEADS * 4);
    int*      offs  = (int*)     carve((size_t)NCH * NBP * 4);
    int*      offsT = (int*)     carve((size_t)NBP * NCH * 4);
    unsigned* stg   = (unsigned*)carve((size_t)N_EDGES * 4);

    k_prep<<<NCH + NNODE, 512, 0, stream>>>(x, W, att_s, att_d, ei, h,
                                            a_srcb, a_dst, offs, stg);
    k_tr<<<100, 256, 0, stream>>>(offs, offsT);
    k_gather<<<NB, 512, 0, stream>>>(h, a_srcb, a_dst, offsT, stg,
                                     bias, fc_w, fc_b, out);
}

// Round 11
// 218.066 us; speedup vs baseline: 6.7257x; 6.7257x over previous
//
#include <hip/hip_runtime.h>
#include <hip/hip_bf16.h>
#include <math.h>

#define N_NODES 100000
#define N_EDGES 1600000
#define HEADS 8
#define HC 128
#define LOG2E 1.44269504f

#define DPB 64                    // dests per bucket
#define NB 1563                   // ceil(100000/64)
#define NBP (NB + 1)              // offsets rows (with end sentinel)
#define NCH 256                   // edge chunks (1.6M/256 = 6250 exact)
#define EPC (N_EDGES / NCH)       // 6250
#define CAPS 2048                 // per-bucket LDS cap (mean ~1088, max ~1300)
#define NNODE 512                 // node-role blocks in k_prep

// ============ K1: fused node transform (blocks >= NCH) + counting sort =======
__global__ __launch_bounds__(512) void k_prep(
    const float* __restrict__ x, const float* __restrict__ W,
    const float* __restrict__ att_s, const float* __restrict__ att_d,
    const int* __restrict__ ei, __hip_bfloat162* __restrict__ h,
    float* __restrict__ a_src, float* __restrict__ a_dst,
    int* __restrict__ offs, unsigned* __restrict__ stg) {
    __shared__ int smem[2048 + EPC];     // csort: hist[2048] + entries[EPC]
    __shared__ int ws8[8];               // node: reuses smem[0..2048) as sW
    int t = threadIdx.x;
    if (blockIdx.x >= NCH) {
        // ---- node role: h = x@W (bf16), logits pre-scaled by LOG2E ----
        float* sW = (float*)smem;
        for (int i = t; i < 16 * HC; i += 512) sW[i] = W[i];
        __syncthreads();
        int lane = t & 63, wv = t >> 6;
        int gw = (blockIdx.x - NCH) * 8 + wv;
        int c0 = 2 * lane;
        float as0 = att_s[c0] * LOG2E, as1 = att_s[c0 + 1] * LOG2E;
        float ad0 = att_d[c0] * LOG2E, ad1 = att_d[c0 + 1] * LOG2E;
        for (int node = gw; node < N_NODES; node += NNODE * 8) {
            float xv = 0.f;
            if (lane < 16) xv = x[node * 16 + lane];
            float acc0 = 0.f, acc1 = 0.f;
#pragma unroll
            for (int k = 0; k < 16; ++k) {
                float xk = __shfl(xv, k);
                acc0 = fmaf(xk, sW[k * HC + c0], acc0);
                acc1 = fmaf(xk, sW[k * HC + c0 + 1], acc1);
            }
            h[node * 64 + lane] = __float22bfloat162_rn(float2{acc0, acc1});
            float ps = acc0 * as0 + acc1 * as1;
            float pd = acc0 * ad0 + acc1 * ad1;
#pragma unroll
            for (int off = 4; off >= 1; off >>= 1) {
                ps += __shfl_xor(ps, off);
                pd += __shfl_xor(pd, off);
            }
            if ((lane & 7) == 0) {
                int hd = lane >> 3;
                a_src[node * HEADS + hd] = ps;
                a_dst[node * HEADS + hd] = pd;
            }
        }
    } else {
        // ---- csort role: bucket-sort chunk edges, write offsets row ----
        int* hist = smem;
        unsigned* entries = (unsigned*)(smem + 2048);
        int c = blockIdx.x;
        hist[t] = 0; hist[t + 512] = 0; hist[t + 1024] = 0; hist[t + 1536] = 0;
        __syncthreads();
        int beg = c * EPC, end = beg + EPC;
        for (int e = beg + t; e < end; e += 512)
            atomicAdd(&hist[ei[N_EDGES + e] >> 6], 1);
        __syncthreads();
        int i0 = 4 * t;
        int v0 = hist[i0], v1 = hist[i0 + 1], v2 = hist[i0 + 2], v3 = hist[i0 + 3];
        int s1 = v0 + v1, s2 = s1 + v2, T = s2 + v3;
        int lane = t & 63, wv = t >> 6;
        int inc = T;
#pragma unroll
        for (int off = 1; off < 64; off <<= 1) {
            int y = __shfl_up(inc, off);
            if (lane >= off) inc += y;
        }
        if (lane == 63) ws8[wv] = inc;
        __syncthreads();
        int wbase = 0;
        for (int k = 0; k < wv; ++k) wbase += ws8[k];
        int e0 = wbase + inc - T;
        hist[i0] = e0; hist[i0 + 1] = e0 + v0;
        hist[i0 + 2] = e0 + s1; hist[i0 + 3] = e0 + s2;
        __syncthreads();
        int row = c * NBP;
        for (int b = t; b < NB; b += 512) offs[row + b] = hist[b];
        if (t == 0) offs[row + NB] = EPC;
        __syncthreads();
        for (int e = beg + t; e < end; e += 512) {
            int src = ei[e], dst = ei[N_EDGES + e];
            int pos = atomicAdd(&hist[dst >> 6], 1);
            entries[pos] = ((unsigned)(dst & 63) << 17) | (unsigned)src;
        }
        __syncthreads();
        unsigned* so = stg + beg;
        for (int i = t; i < EPC; i += 512) so[i] = entries[i];
    }
}

// ============ K2: transpose offs [NCH][NBP] -> offsT [NBP][NCH] ==============
__global__ __launch_bounds__(256) void k_tr(const int* __restrict__ offs,
                                            int* __restrict__ offsT) {
    __shared__ int tile[64][65];
    int b0 = (blockIdx.x >> 2) * 64;
    int c0 = (blockIdx.x & 3) * 64;
    int t = threadIdx.x;
    for (int i = t; i < 4096; i += 256) {
        int cc = i >> 6, bb = i & 63;
        int b = b0 + bb;
        tile[bb][cc] = (b < NBP) ? offs[(c0 + cc) * NBP + b] : 0;
    }
    __syncthreads();
    for (int i = t; i < 4096; i += 256) {
        int bb = i >> 6, cc = i & 63;
        int b = b0 + bb;
        if (b < NBP) offsT[b * NCH + c0 + cc] = tile[bb][cc];
    }
}

// ============ K3: gather (512 thr): seg copy -> LDS dest-sort -> FC ==========
#define EDGE_BODY(SRC) {                                                      \
    int src_ = (SRC);                                                         \
    float e_ = a_src[src_ * 8 + head] + ad;                                   \
    float el_ = fmaxf(e_, 0.2f * e_);                                         \
    float w_ = exp2f(el_);                                                    \
    union { uint2 u; __hip_bfloat162 bb_[2]; } cv_;                           \
    cv_.u = *(const uint2*)(h + (size_t)src_ * 64 + q * 2);                   \
    float2 f01_ = __bfloat1622float2(cv_.bb_[0]);                             \
    float2 f23_ = __bfloat1622float2(cv_.bb_[1]);                             \
    acc0 = fmaf(w_, f01_.x, acc0); acc1 = fmaf(w_, f01_.y, acc1);             \
    acc2 = fmaf(w_, f23_.x, acc2); acc3 = fmaf(w_, f23_.y, acc3);             \
    wsum += w_; }

__global__ __launch_bounds__(512) void k_gather(
    const __hip_bfloat162* __restrict__ h, const float* __restrict__ a_src,
    const float* __restrict__ a_dst, const int* __restrict__ offsT,
    const unsigned* __restrict__ stg, const float* __restrict__ bias,
    const float* __restrict__ fc_w, const float* __restrict__ fc_b,
    float* __restrict__ out) {
    __shared__ unsigned estage[CAPS];
    __shared__ int cstage[CAPS];
    __shared__ int o0_s[NCH];
    __shared__ int myb_s[NCH + 1];
    __shared__ int hist[DPB];
    __shared__ int bs[DPB + 1];
    __shared__ int ws4[4];
    int b = blockIdx.x, t = threadIdx.x;
    int d0 = b * DPB;
    // phase 1: segment starts/lengths (coalesced rows of offsT; threads 0-255)
    int lane = t & 63, wv = t >> 6;
    if (t < NCH) {
        int o0 = offsT[b * NCH + t];
        int len = offsT[(b + 1) * NCH + t] - o0;
        o0_s[t] = o0;
        int inc = len;
#pragma unroll
        for (int off = 1; off < 64; off <<= 1) {
            int y = __shfl_up(inc, off);
            if (lane >= off) inc += y;
        }
        if (lane == 63) ws4[wv] = inc;
        __syncthreads();
        int wbase = 0;
        for (int k = 0; k < wv; ++k) wbase += ws4[k];
        myb_s[t] = wbase + inc - len;
        if (t == 255) myb_s[NCH] = wbase + inc;
    } else {
        __syncthreads();
    }
    if (t < DPB) hist[t] = (d0 + t < N_NODES) ? 1 : 0;   // self loop pre-count
    __syncthreads();
    int tot = myb_s[NCH];
    // phase 2: cooperative coalesced copy (binary search chunk per entry)
    for (int i = t; i < tot; i += 512) {
        int lo = 0, hi = NCH - 1;
#pragma unroll
        for (int s = 0; s < 8; ++s) {
            int mid = (lo + hi + 1) >> 1;
            if (myb_s[mid] <= i) lo = mid; else hi = mid - 1;
        }
        estage[i] = stg[lo * EPC + o0_s[lo] + (i - myb_s[lo])];
    }
    __syncthreads();
    // phase 3: dest histogram
    for (int i = t; i < tot; i += 512) atomicAdd(&hist[estage[i] >> 17], 1);
    __syncthreads();
    // phase 4: 64-scan by wave 0, place self loops, init cursors
    if (t < 64) {
        int v = hist[t];
        int iv = v;
#pragma unroll
        for (int off = 1; off < 64; off <<= 1) {
            int y = __shfl_up(iv, off);
            if (t >= off) iv += y;
        }
        int excl = iv - v;
        bs[t] = excl;
        if (t == 63) bs[64] = iv;
        int gd = d0 + t;
        bool val = gd < N_NODES;
        if (val) cstage[excl] = gd;
        hist[t] = excl + (val ? 1 : 0);
    }
    __syncthreads();
    // phase 5: place edges dest-sorted
    for (int i = t; i < tot; i += 512) {
        unsigned u = estage[i];
        int pos = atomicAdd(&hist[u >> 17], 1);
        cstage[pos] = (int)(u & 0x1FFFF);
    }
    __syncthreads();
    // phase 6: gather + bias/relu + FC + log_softmax (16 groups x 4 dests)
    int q = t & 31, g = t >> 5;
    int head = q >> 2, c0 = q * 4;
    float b0 = bias[c0], b1 = bias[c0 + 1], b2 = bias[c0 + 2], b3 = bias[c0 + 3];
    float fw[4][5], fb[5];
#pragma unroll
    for (int k = 0; k < 4; ++k)
#pragma unroll
        for (int j = 0; j < 5; ++j) fw[k][j] = fc_w[(c0 + k) * 5 + j];
#pragma unroll
    for (int j = 0; j < 5; ++j) fb[j] = fc_b[j];
    for (int l4 = 0; l4 < 4; ++l4) {
        int l = g * 4 + l4;
        int gd = d0 + l;
        if (gd >= N_NODES) break;
        int beg = bs[l], end = bs[l + 1];
        float ad = a_dst[gd * 8 + head];
        float acc0 = 0.f, acc1 = 0.f, acc2 = 0.f, acc3 = 0.f, wsum = 0.f;
        for (int j = beg; j < end; ++j) EDGE_BODY(cstage[j])
        float inv = 1.f / (wsum + 1e-16f);
        float ov0 = fmaxf(acc0 * inv + b0, 0.f);
        float ov1 = fmaxf(acc1 * inv + b1, 0.f);
        float ov2 = fmaxf(acc2 * inv + b2, 0.f);
        float ov3 = fmaxf(acc3 * inv + b3, 0.f);
        float p[5];
#pragma unroll
        for (int j = 0; j < 5; ++j)
            p[j] = ov0 * fw[0][j] + ov1 * fw[1][j] + ov2 * fw[2][j] + ov3 * fw[3][j];
#pragma unroll
        for (int off = 16; off >= 1; off >>= 1) {
#pragma unroll
            for (int j = 0; j < 5; ++j) p[j] += __shfl_xor(p[j], off);
        }
        if (q == 0) {
            float lg[5], m = -1e30f;
#pragma unroll
            for (int j = 0; j < 5; ++j) { lg[j] = p[j] + fb[j]; m = fmaxf(m, lg[j]); }
            float sum = 0.f;
#pragma unroll
            for (int j = 0; j < 5; ++j) sum += __expf(lg[j] - m);
            float ls = m + __logf(sum);
#pragma unroll
            for (int j = 0; j < 5; ++j) out[gd * 5 + j] = lg[j] - ls;
        }
    }
}

extern "C" void kernel_launch(void* const* d_in, const int* in_sizes, int n_in,
                              void* d_out, int out_size, void* d_ws, size_t ws_size,
                              hipStream_t stream) {
    const float* x     = (const float*)d_in[0];
    const int*   ei    = (const int*)d_in[1];
    const float* W     = (const float*)d_in[2];
    const float* att_s = (const float*)d_in[3];
    const float* att_d = (const float*)d_in[4];
    const float* bias  = (const float*)d_in[5];
    const float* fc_w  = (const float*)d_in[6];
    const float* fc_b  = (const float*)d_in[7];
    float* out = (float*)d_out;

    char* ws = (char*)d_ws;
    size_t off = 0;
    auto carve = [&](size_t bytes) {
        void* p = ws + off;
        off = (off + bytes + 255) & ~(size_t)255;
        return p;
    };
    __hip_bfloat162* h = (__hip_bfloat162*)carve((size_t)N_NODES * HC * 2);
    float*    a_src = (float*)   carve((size_t)N_NODES * HEADS * 4);
    float*    a_dst = (float*)   carve((size_t)N_NODES * HEADS * 4);
    int*      offs  = (int*)     carve((size_t)NCH * NBP * 4);
    int*      offsT = (int*)     carve((size_t)NBP * NCH * 4);
    unsigned* stg   = (unsigned*)carve((size_t)N_EDGES * 4);

    k_prep<<<NCH + NNODE, 512, 0, stream>>>(x, W, att_s, att_d, ei, h,
                                            a_src, a_dst, offs, stg);
    k_tr<<<100, 256, 0, stream>>>(offs, offsT);
    k_gather<<<NB, 512, 0, stream>>>(h, a_src, a_dst, offsT, stg,
                                     bias, fc_w, fc_b, out);
}

// Round 13
// 203.794 us; speedup vs baseline: 7.1967x; 1.0700x over previous
//
#include <hip/hip_runtime.h>
#include <hip/hip_bf16.h>
#include <math.h>

#define N_NODES 100000
#define N_EDGES 1600000
#define HEADS 8
#define HC 128
#define LOG2E 1.44269504f

#define DPB 64                    // dests per bucket
#define NB 1563                   // ceil(100000/64)
#define NBP (NB + 1)              // offsets rows (with end sentinel)
#define NCH 256                   // edge chunks (1.6M/256 = 6250 exact)
#define EPC (N_EDGES / NCH)       // 6250
#define CAPS 2048                 // per-bucket LDS cap (mean ~1088, max ~1300)
#define NNODE 512                 // node-role blocks in k_prep

typedef float v2f __attribute__((ext_vector_type(2)));

// ============ K1: fused node transform (blocks >= NCH) + counting sort =======
// node role: h = x@W stored FP8 e4m3 (128 B/row), logits pre-scaled by LOG2E.
__global__ __launch_bounds__(512) void k_prep(
    const float* __restrict__ x, const float* __restrict__ W,
    const float* __restrict__ att_s, const float* __restrict__ att_d,
    const int* __restrict__ ei, unsigned short* __restrict__ h8,
    float* __restrict__ a_src, float* __restrict__ a_dst,
    int* __restrict__ offs, unsigned* __restrict__ stg) {
    __shared__ int smem[2048 + EPC];     // csort: hist[2048] + entries[EPC]
    __shared__ int ws8[8];               // node: reuses smem[0..2048) as sW
    int t = threadIdx.x;
    if (blockIdx.x >= NCH) {
        // ---- node role ----
        float* sW = (float*)smem;
        for (int i = t; i < 16 * HC; i += 512) sW[i] = W[i];
        __syncthreads();
        int lane = t & 63, wv = t >> 6;
        int gw = (blockIdx.x - NCH) * 8 + wv;
        int c0 = 2 * lane;
        float as0 = att_s[c0] * LOG2E, as1 = att_s[c0 + 1] * LOG2E;
        float ad0 = att_d[c0] * LOG2E, ad1 = att_d[c0 + 1] * LOG2E;
        for (int node = gw; node < N_NODES; node += NNODE * 8) {
            float xv = 0.f;
            if (lane < 16) xv = x[node * 16 + lane];
            float acc0 = 0.f, acc1 = 0.f;
#pragma unroll
            for (int k = 0; k < 16; ++k) {
                float xk = __shfl(xv, k);
                acc0 = fmaf(xk, sW[k * HC + c0], acc0);
                acc1 = fmaf(xk, sW[k * HC + c0 + 1], acc1);
            }
            // pack 2 consecutive channels as fp8 e4m3 (OCP native on gfx950)
            int pk = __builtin_amdgcn_cvt_pk_fp8_f32(acc0, acc1, 0, false);
            h8[node * 64 + lane] = (unsigned short)(pk & 0xFFFF);
            float ps = acc0 * as0 + acc1 * as1;
            float pd = acc0 * ad0 + acc1 * ad1;
#pragma unroll
            for (int off = 4; off >= 1; off >>= 1) {
                ps += __shfl_xor(ps, off);
                pd += __shfl_xor(pd, off);
            }
            if ((lane & 7) == 0) {
                int hd = lane >> 3;
                a_src[node * HEADS + hd] = ps;
                a_dst[node * HEADS + hd] = pd;
            }
        }
    } else {
        // ---- csort role: bucket-sort chunk edges, write offsets row ----
        int* hist = smem;
        unsigned* entries = (unsigned*)(smem + 2048);
        int c = blockIdx.x;
        hist[t] = 0; hist[t + 512] = 0; hist[t + 1024] = 0; hist[t + 1536] = 0;
        __syncthreads();
        int beg = c * EPC, end = beg + EPC;
        for (int e = beg + t; e < end; e += 512)
            atomicAdd(&hist[ei[N_EDGES + e] >> 6], 1);
        __syncthreads();
        int i0 = 4 * t;
        int v0 = hist[i0], v1 = hist[i0 + 1], v2 = hist[i0 + 2], v3 = hist[i0 + 3];
        int s1 = v0 + v1, s2 = s1 + v2, T = s2 + v3;
        int lane = t & 63, wv = t >> 6;
        int inc = T;
#pragma unroll
        for (int off = 1; off < 64; off <<= 1) {
            int y = __shfl_up(inc, off);
            if (lane >= off) inc += y;
        }
        if (lane == 63) ws8[wv] = inc;
        __syncthreads();
        int wbase = 0;
        for (int k = 0; k < wv; ++k) wbase += ws8[k];
        int e0 = wbase + inc - T;
        hist[i0] = e0; hist[i0 + 1] = e0 + v0;
        hist[i0 + 2] = e0 + s1; hist[i0 + 3] = e0 + s2;
        __syncthreads();
        int row = c * NBP;
        for (int b = t; b < NB; b += 512) offs[row + b] = hist[b];
        if (t == 0) offs[row + NB] = EPC;
        __syncthreads();
        for (int e = beg + t; e < end; e += 512) {
            int src = ei[e], dst = ei[N_EDGES + e];
            int pos = atomicAdd(&hist[dst >> 6], 1);
            entries[pos] = ((unsigned)(dst & 63) << 17) | (unsigned)src;
        }
        __syncthreads();
        unsigned* so = stg + beg;
        for (int i = t; i < EPC; i += 512) so[i] = entries[i];
    }
}

// ============ K2: transpose offs [NCH][NBP] -> offsT [NBP][NCH] ==============
__global__ __launch_bounds__(256) void k_tr(const int* __restrict__ offs,
                                            int* __restrict__ offsT) {
    __shared__ int tile[64][65];
    int b0 = (blockIdx.x >> 2) * 64;
    int c0 = (blockIdx.x & 3) * 64;
    int t = threadIdx.x;
    for (int i = t; i < 4096; i += 256) {
        int cc = i >> 6, bb = i & 63;
        int b = b0 + bb;
        tile[bb][cc] = (b < NBP) ? offs[(c0 + cc) * NBP + b] : 0;
    }
    __syncthreads();
    for (int i = t; i < 4096; i += 256) {
        int bb = i >> 6, cc = i & 63;
        int b = b0 + bb;
        if (b < NBP) offsT[b * NCH + c0 + cc] = tile[bb][cc];
    }
}

// ============ K3: gather (512 thr): seg copy -> LDS dest-sort -> FC ==========
// h row now fp8: 32-lane group reads 128 B (4 B/lane), 2 lines per edge.
#define EDGE_BODY(SRC) {                                                      \
    int src_ = (SRC);                                                         \
    float e_ = a_src[src_ * 8 + head] + ad;                                   \
    float el_ = fmaxf(e_, 0.2f * e_);                                         \
    float w_ = exp2f(el_);                                                    \
    unsigned hv_ = *(const unsigned*)(h8 + (size_t)src_ * 64 + q * 2);        \
    v2f f01_ = __builtin_amdgcn_cvt_pk_f32_fp8(hv_, false);                   \
    v2f f23_ = __builtin_amdgcn_cvt_pk_f32_fp8(hv_, true);                    \
    acc0 = fmaf(w_, f01_.x, acc0); acc1 = fmaf(w_, f01_.y, acc1);             \
    acc2 = fmaf(w_, f23_.x, acc2); acc3 = fmaf(w_, f23_.y, acc3);             \
    wsum += w_; }

__global__ __launch_bounds__(512) void k_gather(
    const unsigned short* __restrict__ h8, const float* __restrict__ a_src,
    const float* __restrict__ a_dst, const int* __restrict__ offsT,
    const unsigned* __restrict__ stg, const float* __restrict__ bias,
    const float* __restrict__ fc_w, const float* __restrict__ fc_b,
    float* __restrict__ out) {
    __shared__ unsigned estage[CAPS];
    __shared__ int cstage[CAPS];
    __shared__ int o0_s[NCH];
    __shared__ int myb_s[NCH + 1];
    __shared__ int hist[DPB];
    __shared__ int bs[DPB + 1];
    __shared__ int ws4[4];
    int b = blockIdx.x, t = threadIdx.x;
    int d0 = b * DPB;
    // phase 1: segment starts/lengths (coalesced rows of offsT; threads 0-255)
    int lane = t & 63, wv = t >> 6;
    if (t < NCH) {
        int o0 = offsT[b * NCH + t];
        int len = offsT[(b + 1) * NCH + t] - o0;
        o0_s[t] = o0;
        int inc = len;
#pragma unroll
        for (int off = 1; off < 64; off <<= 1) {
            int y = __shfl_up(inc, off);
            if (lane >= off) inc += y;
        }
        if (lane == 63) ws4[wv] = inc;
        __syncthreads();
        int wbase = 0;
        for (int k = 0; k < wv; ++k) wbase += ws4[k];
        myb_s[t] = wbase + inc - len;
        if (t == 255) myb_s[NCH] = wbase + inc;
    } else {
        __syncthreads();
    }
    if (t < DPB) hist[t] = (d0 + t < N_NODES) ? 1 : 0;   // self loop pre-count
    __syncthreads();
    int tot = myb_s[NCH];
    // phase 2: cooperative coalesced copy (binary search chunk per entry)
    for (int i = t; i < tot; i += 512) {
        int lo = 0, hi = NCH - 1;
#pragma unroll
        for (int s = 0; s < 8; ++s) {
            int mid = (lo + hi + 1) >> 1;
            if (myb_s[mid] <= i) lo = mid; else hi = mid - 1;
        }
        estage[i] = stg[lo * EPC + o0_s[lo] + (i - myb_s[lo])];
    }
    __syncthreads();
    // phase 3: dest histogram
    for (int i = t; i < tot; i += 512) atomicAdd(&hist[estage[i] >> 17], 1);
    __syncthreads();
    // phase 4: 64-scan by wave 0, place self loops, init cursors
    if (t < 64) {
        int v = hist[t];
        int iv = v;
#pragma unroll
        for (int off = 1; off < 64; off <<= 1) {
            int y = __shfl_up(iv, off);
            if (t >= off) iv += y;
        }
        int excl = iv - v;
        bs[t] = excl;
        if (t == 63) bs[64] = iv;
        int gd = d0 + t;
        bool val = gd < N_NODES;
        if (val) cstage[excl] = gd;
        hist[t] = excl + (val ? 1 : 0);
    }
    __syncthreads();
    // phase 5: place edges dest-sorted
    for (int i = t; i < tot; i += 512) {
        unsigned u = estage[i];
        int pos = atomicAdd(&hist[u >> 17], 1);
        cstage[pos] = (int)(u & 0x1FFFF);
    }
    __syncthreads();
    // phase 6: gather + bias/relu + FC + log_softmax (16 groups x 4 dests)
    int q = t & 31, g = t >> 5;
    int head = q >> 2, c0 = q * 4;
    float b0 = bias[c0], b1 = bias[c0 + 1], b2 = bias[c0 + 2], b3 = bias[c0 + 3];
    float fw[4][5], fb[5];
#pragma unroll
    for (int k = 0; k < 4; ++k)
#pragma unroll
        for (int j = 0; j < 5; ++j) fw[k][j] = fc_w[(c0 + k) * 5 + j];
#pragma unroll
    for (int j = 0; j < 5; ++j) fb[j] = fc_b[j];
    for (int l4 = 0; l4 < 4; ++l4) {
        int l = g * 4 + l4;
        int gd = d0 + l;
        if (gd >= N_NODES) break;
        int beg = bs[l], end = bs[l + 1];
        float ad = a_dst[gd * 8 + head];
        float acc0 = 0.f, acc1 = 0.f, acc2 = 0.f, acc3 = 0.f, wsum = 0.f;
        for (int j = beg; j < end; ++j) EDGE_BODY(cstage[j])
        float inv = 1.f / (wsum + 1e-16f);
        float ov0 = fmaxf(acc0 * inv + b0, 0.f);
        float ov1 = fmaxf(acc1 * inv + b1, 0.f);
        float ov2 = fmaxf(acc2 * inv + b2, 0.f);
        float ov3 = fmaxf(acc3 * inv + b3, 0.f);
        float p[5];
#pragma unroll
        for (int j = 0; j < 5; ++j)
            p[j] = ov0 * fw[0][j] + ov1 * fw[1][j] + ov2 * fw[2][j] + ov3 * fw[3][j];
#pragma unroll
        for (int off = 16; off >= 1; off >>= 1) {
#pragma unroll
            for (int j = 0; j < 5; ++j) p[j] += __shfl_xor(p[j], off);
        }
        if (q == 0) {
            float lg[5], m = -1e30f;
#pragma unroll
            for (int j = 0; j < 5; ++j) { lg[j] = p[j] + fb[j]; m = fmaxf(m, lg[j]); }
            float sum = 0.f;
#pragma unroll
            for (int j = 0; j < 5; ++j) sum += __expf(lg[j] - m);
            float ls = m + __logf(sum);
#pragma unroll
            for (int j = 0; j < 5; ++j) out[gd * 5 + j] = lg[j] - ls;
        }
    }
}

extern "C" void kernel_launch(void* const* d_in, const int* in_sizes, int n_in,
                              void* d_out, int out_size, void* d_ws, size_t ws_size,
                              hipStream_t stream) {
    const float* x     = (const float*)d_in[0];
    const int*   ei    = (const int*)d_in[1];
    const float* W     = (const float*)d_in[2];
    const float* att_s = (const float*)d_in[3];
    const float* att_d = (const float*)d_in[4];
    const float* bias  = (const float*)d_in[5];
    const float* fc_w  = (const float*)d_in[6];
    const float* fc_b  = (const float*)d_in[7];
    float* out = (float*)d_out;

    char* ws = (char*)d_ws;
    size_t off = 0;
    auto carve = [&](size_t bytes) {
        void* p = ws + off;
        off = (off + bytes + 255) & ~(size_t)255;
        return p;
    };
    unsigned short* h8 = (unsigned short*)carve((size_t)N_NODES * 64 * 2); // fp8 x128
    float*    a_src = (float*)   carve((size_t)N_NODES * HEADS * 4);
    float*    a_dst = (float*)   carve((size_t)N_NODES * HEADS * 4);
    int*      offs  = (int*)     carve((size_t)NCH * NBP * 4);
    int*      offsT = (int*)     carve((size_t)NBP * NCH * 4);
    unsigned* stg   = (unsigned*)carve((size_t)N_EDGES * 4);

    k_prep<<<NCH + NNODE, 512, 0, stream>>>(x, W, att_s, att_d, ei, h8,
                                            a_src, a_dst, offs, stg);
    k_tr<<<100, 256, 0, stream>>>(offs, offsT);
    k_gather<<<NB, 512, 0, stream>>>(h8, a_src, a_dst, offsT, stg,
                                     bias, fc_w, fc_b, out);
}